// Round 5
// baseline (553.740 us; speedup 1.0000x reference)
//
#include <hip/hip_runtime.h>

// Problem: y[d,k,:] = (x[n]*sn[n]) @ (w[:256]+w[256:]) + b, n = domains[d,k]
// Structure: inverse-index scatter (R4) + MFMA bf16-split GEMM (this round).
// z = xh*wh + xh*wl + xl*wh (Markidis 3-term, fp32 accumulate) — ~1e-5 abs
// error vs fp32, far under the tolerance evidenced by absmax=0.015625 across
// three different fp32 orderings (ref-side quantization dominates).

#define GM 50000
#define GK 256
#define GN 256
#define RTOT 400000      // 25000 * 16 output rows
#define BM 128
#define BN 128
#define BK 32
#define LDK 40           // padded k-pitch (ushorts): 80 B row, conflict-free frag reads
#define CAP 64           // max dup-count per node; Poisson(8) max over 50K ~ 30
#define OVF_MAX 4096

using bf16x8 = __attribute__((ext_vector_type(8))) short;
using f32x4  = __attribute__((ext_vector_type(4))) float;

__device__ inline ushort f2bf(float f) {          // round-to-nearest-even
    uint u = __float_as_uint(f);
    u += 0x7FFFu + ((u >> 16) & 1u);
    return (ushort)(u >> 16);
}
__device__ inline float bf2f(ushort h) { return __uint_as_float(((uint)h) << 16); }

__global__ __launch_bounds__(256)
void zero_kernel(int* __restrict__ cnt, int* __restrict__ ovf_cnt) {
    const int i = blockIdx.x * 256 + threadIdx.x;
    if (i < GM) cnt[i] = 0;
    if (i == 0) *ovf_cnt = 0;
}

// Inverse index: bucket[n*CAP + j] = output rows r with domains[r]==n.
__global__ __launch_bounds__(256)
void build_kernel(const int* __restrict__ dm, int* __restrict__ cnt,
                  int* __restrict__ bucket, int* __restrict__ ovf,
                  int* __restrict__ ovf_cnt) {
    const int r = blockIdx.x * 256 + threadIdx.x;
    if (r >= RTOT) return;
    const int n = dm[r];
    const int slot = atomicAdd(&cnt[n], 1);
    if (slot < CAP) {
        bucket[n * CAP + slot] = r;
    } else {
        const int o = atomicAdd(ovf_cnt, 1);
        if (o < OVF_MAX) ovf[o] = r;
    }
}

// weff = w[:256]+w[256:], split to bf16 hi/lo, stored TRANSPOSED [N][K] so the
// GEMM stages B-fragments with contiguous-k b128 reads (same layout as A).
__global__ __launch_bounds__(256)
void wsplit_kernel(const float* __restrict__ w, ushort* __restrict__ whT,
                   ushort* __restrict__ wlT) {
    const int idx = blockIdx.x * 256 + threadIdx.x;   // 65536 elements
    const int k = idx >> 8, n = idx & 255;
    const float we = w[k * GN + n] + w[(k + 256) * GN + n];
    const ushort hi = f2bf(we);
    const ushort lo = f2bf(we - bf2f(hi));
    whT[n * GK + k] = hi;
    wlT[n * GK + k] = lo;
}

// MFMA GEMM (128x128 tile, 256 thr = 4 waves, each wave 64x64 via 4x4 frags of
// 16x16x32_bf16) + scatter epilogue through the inverse index.
__global__ __launch_bounds__(256)
void gemm_scatter_kernel(const float* __restrict__ x,
                         const float* __restrict__ sn,
                         const ushort* __restrict__ whT,
                         const ushort* __restrict__ wlT,
                         const float* __restrict__ b,
                         const int* __restrict__ cnt,
                         const int* __restrict__ bucket,
                         float* __restrict__ out,
                         float* __restrict__ z) {
    __shared__ ushort Ah[BM][LDK];   // 10240 B each, 40 KB total -> 4 blocks/CU
    __shared__ ushort Al[BM][LDK];
    __shared__ ushort Bh[BN][LDK];
    __shared__ ushort Bl[BN][LDK];

    const int t = threadIdx.x;
    const int rowBase = blockIdx.x * BM;
    const int colBase = blockIdx.y * BN;

    // staging map: thread t handles LDS row t>>1, k-half (t&1)*16
    const int srow = t >> 1;
    const int skh  = (t & 1) * 16;

    // wave/lane -> fragment coordinates
    const int wid  = t >> 6;
    const int lane = t & 63;
    const int fr   = lane & 15;      // frag col (A/B row sel, C col)
    const int fq   = lane >> 4;      // k-slot group / C row group
    const int wm   = (wid >> 1) * 64;
    const int wn   = (wid & 1) * 64;

    f32x4 acc[4][4];
    #pragma unroll
    for (int i = 0; i < 4; ++i)
        #pragma unroll
        for (int j = 0; j < 4; ++j)
            acc[i][j] = (f32x4){0.f, 0.f, 0.f, 0.f};

    for (int k0 = 0; k0 < GK; k0 += BK) {
        // --- stage A: load x row-slice, scale by sn, split hi/lo bf16 ---
        {
            const int m = rowBase + srow;
            float v[16];
            if (m < GM) {
                const float s = sn[m];
                const float4* xp =
                    reinterpret_cast<const float4*>(&x[(size_t)m * GK + k0 + skh]);
                #pragma unroll
                for (int q = 0; q < 4; ++q) {
                    const float4 f = xp[q];
                    v[q*4+0] = f.x * s; v[q*4+1] = f.y * s;
                    v[q*4+2] = f.z * s; v[q*4+3] = f.w * s;
                }
            } else {
                #pragma unroll
                for (int q = 0; q < 16; ++q) v[q] = 0.f;
            }
            union { ushort u[8]; uint4 q4; } h0, h1, l0, l1;
            #pragma unroll
            for (int q = 0; q < 8; ++q) {
                const ushort h = f2bf(v[q]);
                h0.u[q] = h; l0.u[q] = f2bf(v[q] - bf2f(h));
            }
            #pragma unroll
            for (int q = 0; q < 8; ++q) {
                const ushort h = f2bf(v[8 + q]);
                h1.u[q] = h; l1.u[q] = f2bf(v[8 + q] - bf2f(h));
            }
            *reinterpret_cast<uint4*>(&Ah[srow][skh])     = h0.q4;
            *reinterpret_cast<uint4*>(&Ah[srow][skh + 8]) = h1.q4;
            *reinterpret_cast<uint4*>(&Al[srow][skh])     = l0.q4;
            *reinterpret_cast<uint4*>(&Al[srow][skh + 8]) = l1.q4;
        }
        // --- stage B: copy pre-split transposed weights (L2-resident) ---
        {
            const int n = colBase + srow;
            const uint4* ph =
                reinterpret_cast<const uint4*>(&whT[(size_t)n * GK + k0 + skh]);
            const uint4* pl =
                reinterpret_cast<const uint4*>(&wlT[(size_t)n * GK + k0 + skh]);
            *reinterpret_cast<uint4*>(&Bh[srow][skh])     = ph[0];
            *reinterpret_cast<uint4*>(&Bh[srow][skh + 8]) = ph[1];
            *reinterpret_cast<uint4*>(&Bl[srow][skh])     = pl[0];
            *reinterpret_cast<uint4*>(&Bl[srow][skh + 8]) = pl[1];
        }
        __syncthreads();

        // --- fragments + 3-term MFMA ---
        bf16x8 bh[4], bl[4];
        #pragma unroll
        for (int ni = 0; ni < 4; ++ni) {
            const int br = wn + ni * 16 + fr;
            bh[ni] = *reinterpret_cast<const bf16x8*>(&Bh[br][fq * 8]);
            bl[ni] = *reinterpret_cast<const bf16x8*>(&Bl[br][fq * 8]);
        }
        #pragma unroll
        for (int mi = 0; mi < 4; ++mi) {
            const int ar = wm + mi * 16 + fr;
            const bf16x8 ah = *reinterpret_cast<const bf16x8*>(&Ah[ar][fq * 8]);
            const bf16x8 al = *reinterpret_cast<const bf16x8*>(&Al[ar][fq * 8]);
            #pragma unroll
            for (int ni = 0; ni < 4; ++ni) {
                acc[mi][ni] = __builtin_amdgcn_mfma_f32_16x16x32_bf16(
                    ah, bh[ni], acc[mi][ni], 0, 0, 0);
                acc[mi][ni] = __builtin_amdgcn_mfma_f32_16x16x32_bf16(
                    ah, bl[ni], acc[mi][ni], 0, 0, 0);
                acc[mi][ni] = __builtin_amdgcn_mfma_f32_16x16x32_bf16(
                    al, bh[ni], acc[mi][ni], 0, 0, 0);
            }
        }
        __syncthreads();
    }

    // --- scatter epilogue ---
    // C layout (m89-verified): col = lane&15 (fr), row = (lane>>4)*4 + reg (fq,r)
    float bias[4];
    #pragma unroll
    for (int ni = 0; ni < 4; ++ni) bias[ni] = b[colBase + wn + ni * 16 + fr];

    const int ncol0 = colBase + wn + fr;
    #pragma unroll
    for (int mi = 0; mi < 4; ++mi) {
        #pragma unroll
        for (int r = 0; r < 4; ++r) {
            const int m = rowBase + wm + mi * 16 + fq * 4 + r;
            if (m >= GM) continue;
            const float v0 = acc[mi][0][r] + bias[0];
            const float v1 = acc[mi][1][r] + bias[1];
            const float v2 = acc[mi][2][r] + bias[2];
            const float v3 = acc[mi][3][r] + bias[3];
            const int c  = cnt[m];
            const int cc = c < CAP ? c : CAP;
            const int* bk = &bucket[m * CAP];
            for (int j = 0; j < cc; ++j) {
                float* orow = &out[(size_t)bk[j] * GN + ncol0];
                __builtin_nontemporal_store(v0, orow);
                __builtin_nontemporal_store(v1, orow + 16);
                __builtin_nontemporal_store(v2, orow + 32);
                __builtin_nontemporal_store(v3, orow + 48);
            }
            if (c > CAP) {   // overflow escape hatch
                float* zr = &z[(size_t)m * GN + ncol0];
                zr[0] = v0; zr[16] = v1; zr[32] = v2; zr[48] = v3;
            }
        }
    }
}

// Handles bucket-overflow rows (empty in practice): out[r] = z[dm[r]].
__global__ __launch_bounds__(256)
void cleanup_kernel(const float* __restrict__ z, const int* __restrict__ dm,
                    const int* __restrict__ ovf, const int* __restrict__ ovf_cnt,
                    float* __restrict__ out) {
    int nov = *ovf_cnt;
    if (nov > OVF_MAX) nov = OVF_MAX;
    const int lane = threadIdx.x & 63;
    const int wid  = (blockIdx.x * 256 + threadIdx.x) >> 6;
    const int nw   = (gridDim.x * 256) >> 6;
    for (int i = wid; i < nov; i += nw) {
        const int r = ovf[i];
        const int n = dm[r];
        const float4 v = *reinterpret_cast<const float4*>(&z[(size_t)n * GN + lane * 4]);
        *reinterpret_cast<float4*>(&out[(size_t)r * GN + lane * 4]) = v;
    }
}

extern "C" void kernel_launch(void* const* d_in, const int* in_sizes, int n_in,
                              void* d_out, int out_size, void* d_ws, size_t ws_size,
                              hipStream_t stream) {
    const float* x  = (const float*)d_in[0];   // [50000, 256]
    const float* sn = (const float*)d_in[1];   // [50000]
    const int*   dm = (const int*)d_in[2];     // [25000, 16] (int32 per harness)
    const float* w  = (const float*)d_in[3];   // [512, 256]
    const float* b  = (const float*)d_in[4];   // [256]
    float* out = (float*)d_out;                // [25000, 16, 256]

    // Workspace layout (~64.5 MB)
    char* ws = (char*)d_ws;
    float*  z       = (float*)ws;                          // 51,200,000 B
    int*    cnt     = (int*)(ws + 51200000);               // 200,000 B
    int*    bucket  = cnt + GM;                            // 12,800,000 B
    int*    ovf_cnt = bucket + (size_t)GM * CAP;           // 16 B (padded)
    int*    ovf     = ovf_cnt + 4;                         // 16,384 B
    ushort* whT     = (ushort*)(ovf + OVF_MAX);            // 131,072 B
    ushort* wlT     = whT + GK * GN;                       // 131,072 B

    zero_kernel<<<(GM + 255) / 256, 256, 0, stream>>>(cnt, ovf_cnt);
    build_kernel<<<(RTOT + 255) / 256, 256, 0, stream>>>(dm, cnt, bucket, ovf, ovf_cnt);
    wsplit_kernel<<<(GK * GN) / 256, 256, 0, stream>>>(w, whT, wlT);

    dim3 gemm_grid((GM + BM - 1) / BM, GN / BN);           // (391, 2)
    gemm_scatter_kernel<<<gemm_grid, 256, 0, stream>>>(x, sn, whT, wlT, b,
                                                       cnt, bucket, out, z);

    cleanup_kernel<<<64, 256, 0, stream>>>(z, dm, ovf, ovf_cnt, out);
}